// Round 10
// baseline (330.758 us; speedup 1.0000x reference)
//
#include <hip/hip_runtime.h>
#include <hip/hip_fp16.h>

#define NN 100000
#define NE 1600000
#define DF 50
#define NC 47
#define DP 64     // padded feature dim; fp16 row = 128 B = 8 x 16B chunks
#define ZROW NN   // index of the all-zero row (for masked-out gathers)

static_assert(NN % 16 == 0, "grid exactness");
static_assert(NE % 8 == 0, "int4 x2 edge loads");

typedef _Float16 half8 __attribute__((ext_vector_type(8)));
typedef float float4v __attribute__((ext_vector_type(4)));

// Phase 1: counting + slot assignment in ONE pass, 8 edges/thread.
// cursor starts at 0; returned value = in-node position, final cursor = degree.
__global__ void slot_kernel(const int4* __restrict__ dst4, unsigned* __restrict__ cursor,
                            uint4* __restrict__ pslots, int E8) {
    int t = blockIdx.x * blockDim.x + threadIdx.x;
    if (t >= E8) return;
    int4 q0 = dst4[2 * t];
    int4 q1 = dst4[2 * t + 1];
    uint4 p0, p1;
    p0.x = atomicAdd(&cursor[q0.x], 1u);
    p0.y = atomicAdd(&cursor[q0.y], 1u);
    p0.z = atomicAdd(&cursor[q0.z], 1u);
    p0.w = atomicAdd(&cursor[q0.w], 1u);
    p1.x = atomicAdd(&cursor[q1.x], 1u);
    p1.y = atomicAdd(&cursor[q1.y], 1u);
    p1.z = atomicAdd(&cursor[q1.z], 1u);
    p1.w = atomicAdd(&cursor[q1.w], 1u);
    pslots[2 * t]     = p0;
    pslots[2 * t + 1] = p1;
}

// Per-node: dinv/selfw; CSR row allocation via wave scan + one atomic per wave.
__global__ void alloc_kernel(const unsigned* __restrict__ degArr, float* __restrict__ dinv,
                             float* __restrict__ selfw, unsigned* __restrict__ rowStart,
                             unsigned* __restrict__ total, int N) {
    int n = blockIdx.x * blockDim.x + threadIdx.x;
    int lane = threadIdx.x & 63;
    unsigned d = (n < N) ? degArr[n] : 0u;
    unsigned s = d;
    #pragma unroll
    for (int off = 1; off < 64; off <<= 1) {
        unsigned t = __shfl_up(s, off);
        if (lane >= off) s += t;
    }
    unsigned waveSum = __shfl(s, 63);
    unsigned base = 0;
    if (lane == 63) base = atomicAdd(total, waveSum);
    base = __shfl(base, 63);
    if (n < N) {
        rowStart[n] = base + s - d;
        float dd = 1.0f + (float)d;
        float r = rsqrtf(dd);
        dinv[n] = r;
        selfw[n] = r * r;
    }
}

#define SCAT_B ((NE / 4 + 255) / 256)
#define PAD_B  (((NN + 1) * 8 + 255) / 256)

// Grid-split: blocks [0,SCAT_B) scatter cols; blocks [SCAT_B,..) build featp
// (pre-scaled by dinv, fp16, zero-padded; row NN = zeros) and zero h1p's ZROW.
__global__ void scatpad_kernel(const int4* __restrict__ src4, const int4* __restrict__ dst4,
                               const uint4* __restrict__ pslots,
                               const unsigned* __restrict__ rowStart,
                               int* __restrict__ cols,
                               const float* __restrict__ f, const float* __restrict__ dinv,
                               float4* __restrict__ fp, float4* __restrict__ h1p4) {
    if (blockIdx.x < SCAT_B) {
        int t = blockIdx.x * blockDim.x + threadIdx.x;
        if (t >= NE / 4) return;
        int4  s = src4[t];
        int4  q = dst4[t];
        uint4 p = pslots[t];
        unsigned i0 = rowStart[q.x] + p.x;
        unsigned i1 = rowStart[q.y] + p.y;
        unsigned i2 = rowStart[q.z] + p.z;
        unsigned i3 = rowStart[q.w] + p.w;
        __builtin_nontemporal_store(s.x, &cols[i0]);
        __builtin_nontemporal_store(s.y, &cols[i1]);
        __builtin_nontemporal_store(s.z, &cols[i2]);
        __builtin_nontemporal_store(s.w, &cols[i3]);
    } else {
        int t = (blockIdx.x - SCAT_B) * blockDim.x + threadIdx.x;
        if (t >= (NN + 1) * 8) return;
        int n = t >> 3, c = t & 7;
        float sc = (n < NN) ? dinv[n] : 0.f;
        float v[8];
        #pragma unroll
        for (int i = 0; i < 8; ++i) {
            int e = c * 8 + i;
            v[i] = (n < NN && e < DF) ? sc * f[n * DF + e] : 0.f;
        }
        float4 ov;
        __half2* op = (__half2*)&ov;
        #pragma unroll
        for (int i = 0; i < 4; ++i) op[i] = __floats2half2_rn(v[2 * i], v[2 * i + 1]);
        fp[t] = ov;
        if (n == NN) h1p4[t] = make_float4(0.f, 0.f, 0.f, 0.f);  // zero row of h1
    }
}

// One wave per TWO dst nodes. Pure unweighted gather-sum of pre-scaled rows,
// 8 gathers in flight. Epilogue scales by scaleArr[nd] and writes fp16 rows.
__global__ __launch_bounds__(256) void hop_kernel(const _Float16* __restrict__ h,
    const int* __restrict__ cols, const unsigned* __restrict__ rowStart,
    const unsigned* __restrict__ deg, const float* __restrict__ scaleArr,
    _Float16* __restrict__ hn) {

    int lane = threadIdx.x & 63;
    int wid  = (int)((blockIdx.x * blockDim.x + threadIdx.x) >> 6);
    int half = lane >> 5;
    int g    = (lane >> 3) & 3;
    int qid  = lane & 7;

    int nd = 2 * wid + half;
    unsigned rs = rowStart[nd];
    unsigned d  = deg[nd];
    unsigned dmax = max(__shfl(d, 0), __shfl(d, 32));

    float acc[8] = {0.f, 0.f, 0.f, 0.f, 0.f, 0.f, 0.f, 0.f};

    for (unsigned j0 = 0; j0 < dmax; j0 += 32u) {
        #pragma unroll
        for (int u = 0; u < 8; ++u) {
            unsigned j = j0 + (unsigned)(g + 4 * u);
            unsigned idx = min(rs + j, (unsigned)(NE - 1));
            int c = cols[idx];
            c = (j < d) ? c : ZROW;
            half8 v = *(const half8*)(h + (unsigned)c * DP + qid * 8);
            #pragma unroll
            for (int i = 0; i < 8; ++i) acc[i] += (float)v[i];
        }
    }

    #pragma unroll
    for (int i = 0; i < 8; ++i) {
        acc[i] += __shfl_xor(acc[i], 8);
        acc[i] += __shfl_xor(acc[i], 16);
    }

    float s = scaleArr[nd];
    half8 hv = *(const half8*)(h + (unsigned)nd * DP + qid * 8);
    half8 ov;
    #pragma unroll
    for (int i = 0; i < 8; ++i)
        ov[i] = (_Float16)(s * (acc[i] + (float)hv[i]));
    if ((lane & 24) == 0)
        *(half8*)(hn + (unsigned)nd * DP + qid * 8) = ov;
}

// Hop 2 + FC fused. 512 threads = 8 waves = 16 nodes = one MFMA M-tile.
// Hop rows -> LDS (stride 72), sync, waves 0..2 each compute one 16-class tile.
__global__ __launch_bounds__(512) void hop2fc_kernel(const _Float16* __restrict__ h,
    const int* __restrict__ cols, const unsigned* __restrict__ rowStart,
    const unsigned* __restrict__ deg, const float* __restrict__ dinv,
    const float* __restrict__ W, const float* __restrict__ b,
    float* __restrict__ out) {

    __shared__ _Float16 sW[48 * 72];
    __shared__ _Float16 sh[16 * 72];
    __shared__ float    sB[48];

    // stage W (fp32 -> fp16) + bias
    for (int i = threadIdx.x; i < 48 * 64; i += 512) {
        int n = i >> 6, k = i & 63;
        float v = (n < NC && k < DF) ? W[n * DF + k] : 0.f;
        sW[n * 72 + k] = (_Float16)v;
    }
    if (threadIdx.x < 48) sB[threadIdx.x] = (threadIdx.x < NC) ? b[threadIdx.x] : 0.f;

    int lane = threadIdx.x & 63;
    int wib  = threadIdx.x >> 6;               // wave in block 0..7
    int wid  = blockIdx.x * 8 + wib;
    int half = lane >> 5;
    int g    = (lane >> 3) & 3;
    int qid  = lane & 7;

    int nib = 2 * wib + half;                  // node in block 0..15
    int nd  = 2 * wid + half;
    unsigned rs = rowStart[nd];
    unsigned d  = deg[nd];
    unsigned dmax = max(__shfl(d, 0), __shfl(d, 32));

    float acc[8] = {0.f, 0.f, 0.f, 0.f, 0.f, 0.f, 0.f, 0.f};

    for (unsigned j0 = 0; j0 < dmax; j0 += 32u) {
        #pragma unroll
        for (int u = 0; u < 8; ++u) {
            unsigned j = j0 + (unsigned)(g + 4 * u);
            unsigned idx = min(rs + j, (unsigned)(NE - 1));
            int c = cols[idx];
            c = (j < d) ? c : ZROW;
            half8 v = *(const half8*)(h + (unsigned)c * DP + qid * 8);
            #pragma unroll
            for (int i = 0; i < 8; ++i) acc[i] += (float)v[i];
        }
    }

    #pragma unroll
    for (int i = 0; i < 8; ++i) {
        acc[i] += __shfl_xor(acc[i], 8);
        acc[i] += __shfl_xor(acc[i], 16);
    }

    float s = dinv[nd];
    half8 hv = *(const half8*)(h + (unsigned)nd * DP + qid * 8);
    if ((lane & 24) == 0) {
        half8 ov;
        #pragma unroll
        for (int i = 0; i < 8; ++i)
            ov[i] = (_Float16)(s * (acc[i] + (float)hv[i]));
        *(half8*)(sh + nib * 72 + qid * 8) = ov;
    }
    __syncthreads();

    // FC: waves 0..2 each handle one 16-class tile of this block's 16-row tile
    if (wib < 3) {
        int am = lane & 15;                    // row (node in block) / class within tile
        int aq = lane >> 4;                    // k-quad
        half8 a0 = *(const half8*)(sh + am * 72 + aq * 8);
        half8 a1 = *(const half8*)(sh + am * 72 + 32 + aq * 8);
        int n = wib * 16 + am;
        const half8* brow = (const half8*)(sW + n * 72);
        half8 b0 = brow[aq];
        half8 b1 = brow[aq + 4];
        float4v cacc = {0.f, 0.f, 0.f, 0.f};
        cacc = __builtin_amdgcn_mfma_f32_16x16x32_f16(a0, b0, cacc, 0, 0, 0);
        cacc = __builtin_amdgcn_mfma_f32_16x16x32_f16(a1, b1, cacc, 0, 0, 0);
        if (n < NC) {
            int m0 = blockIdx.x * 16;
            int row = aq * 4;
            float bn = sB[n];
            #pragma unroll
            for (int r = 0; r < 4; ++r)
                out[(long)(m0 + row + r) * NC + n] = cacc[r] + bn;
        }
    }
}

extern "C" void kernel_launch(void* const* d_in, const int* in_sizes, int n_in,
                              void* d_out, int out_size, void* d_ws, size_t ws_size,
                              hipStream_t stream) {
    const float* feat = (const float*)d_in[0];
    const float* W    = (const float*)d_in[1];
    const float* b    = (const float*)d_in[2];
    const int*  esrc  = (const int*)d_in[3];
    const int*  edst  = (const int*)d_in[4];
    float* out = (float*)d_out;

    char* ws = (char*)d_ws;
    unsigned* cursor   = (unsigned*)ws; ws += NN * sizeof(unsigned);   // becomes deg after slot
    unsigned* total    = (unsigned*)ws; ws += 4 * sizeof(unsigned);    // memset with cursor
    unsigned* rowStart = (unsigned*)ws; ws += NN * sizeof(unsigned);
    float*    dinv     = (float*)ws;    ws += NN * sizeof(float);
    float*    selfw    = (float*)ws;    ws += NN * sizeof(float);
    unsigned* pslots   = (unsigned*)ws; ws += (size_t)NE * sizeof(unsigned);
    int*      cols     = (int*)ws;      ws += (size_t)NE * sizeof(int);
    _Float16* featp    = (_Float16*)ws; ws += (size_t)(NN + 1) * DP * sizeof(_Float16);
    _Float16* h1p      = (_Float16*)ws;

    hipMemsetAsync(cursor, 0, (NN + 4) * sizeof(unsigned), stream);

    slot_kernel<<<(NE / 8 + 255) / 256, 256, 0, stream>>>((const int4*)edst, cursor,
                                                          (uint4*)pslots, NE / 8);
    alloc_kernel<<<(NN + 255) / 256, 256, 0, stream>>>(cursor, dinv, selfw, rowStart, total, NN);
    scatpad_kernel<<<SCAT_B + PAD_B, 256, 0, stream>>>((const int4*)esrc, (const int4*)edst,
                                                       (const uint4*)pslots, rowStart, cols,
                                                       feat, dinv, (float4*)featp, (float4*)h1p);

    hop_kernel<<<NN / 8, 256, 0, stream>>>(featp, cols, rowStart, cursor, selfw, h1p);
    hop2fc_kernel<<<NN / 16, 512, 0, stream>>>(h1p, cols, rowStart, cursor, dinv, W, b, out);
}